// Round 16
// baseline (22.521 us; speedup 1.0000x reference)
//
#include <hip/hip_runtime.h>
#include <hip/hip_fp16.h>
#include <math.h>

#define NMODES 4096
#define NGRID  8192
#define BATCH  16
#define NPTS   131072
#define GSTRIDE 8200                    // 8192 + 8 wrap cells (u32 each); %4==0
#define GSCALE 1048576.0f               // 2^20 (exact)
#define OSCALE 1.5178830414797062e-07f  // 1/(2*pi*2^20)

__device__ __forceinline__ float2 cmul(float2 a, float2 b) {
    return make_float2(a.x * b.x - a.y * b.y, a.x * b.y + a.y * b.x);
}

__device__ __forceinline__ float2 h2f(unsigned v) {
    __half2 h = *reinterpret_cast<__half2*>(&v);
    return __half22float2(h);
}

// ---------------------------------------------------------------------------
// Deconvolution factor: (-1)^fidx / phi_hat(fidx), I0 asymptotic (z~18).
// ---------------------------------------------------------------------------
__device__ __forceinline__ float deconv_signed(int fidx) {
    float k = (float)(fidx - 2048);
    float t = k * 7.66990393942820614e-4f;                 // 2*pi*k/n
    float z = 4.0f * sqrtf(22.2066099024510563f - t * t);  // m*sqrt(b^2-t^2)
    float iz = 1.0f / z;
    float p  = 1.0f + iz * (0.125f + iz * (0.0703125f +
               iz * (0.0732421875f + iz * 0.112152099609375f)));
    float phi = __expf(z) * p * rsqrtf(6.28318530717958648f * z);
    float s = (fidx & 1) ? -1.0f : 1.0f;
    return s / phi;
}

// ---------------------------------------------------------------------------
// Merged four-step FFT (byte-identical to green R12/R15). One block per
// (batch, k1); writes packed scaled fp16 cells + 8 wrap cells.
// ---------------------------------------------------------------------------
__global__ __launch_bounds__(256) void nfft_fft_kernel(
    const float* __restrict__ fr, const float* __restrict__ fi,
    __half2* __restrict__ g16)
{
    __shared__ float2 hbuf[NMODES];  // 32 KB
    __shared__ float2 fbuf[512];     // 4 KB
    __shared__ float2 w16[16];

    const int b   = blockIdx.x >> 4;
    const int k1  = blockIdx.x & 15;
    const int tid = threadIdx.x;

    if (tid < 16) {
        float tn = -(float)tid * 0.0625f;   // -t/16 turns
        w16[tid] = make_float2(__builtin_amdgcn_cosf(tn),
                               __builtin_amdgcn_sinf(tn));
    }
#pragma unroll
    for (int i = 0; i < 16; ++i) {          // coalesced: lanes consecutive
        int fidx = tid + i * 256;
        float inv = deconv_signed(fidx);    // includes (-1)^j sign
        hbuf[fidx] = make_float2(fr[b * NMODES + fidx] * inv,
                                 fi[b * NMODES + fidx] * inv);
    }
    __syncthreads();

#pragma unroll
    for (int hi = 0; hi < 2; ++hi) {
        int n2 = tid + hi * 256;
        float2 acc = make_float2(0.0f, 0.0f);
#pragma unroll
        for (int r = 0; r < 8; ++r) {
            float2 w = w16[((r + 4) * k1) & 15];
            float2 h = hbuf[n2 + 512 * r];
            acc.x = fmaf(h.x, w.x, fmaf(-h.y, w.y, acc.x));
            acc.y = fmaf(h.x, w.y, fmaf( h.y, w.x, acc.y));
        }
        float tn = -(float)(n2 * k1) * 1.220703125e-4f;  // -(n2*k1)/8192 turns
        float2 tw = make_float2(__builtin_amdgcn_cosf(tn),
                                __builtin_amdgcn_sinf(tn));
        int rb = (int)(__brev((unsigned)n2) >> 23);      // 9-bit reversal
        fbuf[rb] = cmul(acc, tw);
    }
    __syncthreads();

    for (int s = 0; s <= 8; ++s) {
        const int   half = 1 << s;
        const float tscl = -0.5f / (float)half;          // turns per pos
        int pos = tid & (half - 1);
        int idx = ((tid ^ pos) << 1) | pos;
        float sn = __builtin_amdgcn_sinf(tscl * (float)pos);
        float cs = __builtin_amdgcn_cosf(tscl * (float)pos);
        float2 a = fbuf[idx];
        float2 t = fbuf[idx + half];
        float2 bt = make_float2(t.x * cs - t.y * sn,
                                t.x * sn + t.y * cs);
        fbuf[idx]        = make_float2(a.x + bt.x, a.y + bt.y);
        fbuf[idx + half] = make_float2(a.x - bt.x, a.y - bt.y);
        __syncthreads();
    }

    const float s2 = ((k1 & 1) ? -1.0f : 1.0f) * GSCALE;  // sign * 2^20
    __half2* base = g16 + b * GSTRIDE + k1;
#pragma unroll
    for (int ii = 0; ii < 2; ++ii) {
        int j = tid + ii * 256;
        float2 v = fbuf[j];
        base[16 * j] = __floats2half2_rn(v.x * s2, v.y * s2);
    }
    if (tid == 0 && k1 < 8) {   // wrap cell: cell k1 duplicated at 8192+k1
        float2 v = fbuf[0];
        g16[b * GSTRIDE + NGRID + k1] = __floats2half2_rn(v.x * s2, v.y * s2);
    }
}

// ---------------------------------------------------------------------------
// Interp: dual-pipe scatter. The block's packed g16 slab (32.8 KB) is
// pure-copied into LDS; per point, taps 0-3 come from LDS (adjacent dwords
// -> 2x ds_read2_b32) while taps 4-7 come from global/L1 (4 dwords).
// The two memory pipes process their 4-address streams in parallel.
// ---------------------------------------------------------------------------
__global__ __launch_bounds__(1024) void nfft_interp_kernel(
    const float* __restrict__ x, const __half2* __restrict__ g16,
    float* __restrict__ out, int cplx)
{
    __shared__ uint4 gl4[2050];          // 32,800 B: full slab incl. wrap pad

    const int b   = blockIdx.x & 15;    // co-resident blocks share a batch
    const int blk = blockIdx.x >> 4;
    const int tid = threadIdx.x;

    const uint4* gs4 = (const uint4*)(g16 + b * GSTRIDE);
    for (int i = tid; i < 2050; i += 1024) gl4[i] = gs4[i];   // pure copy
    __syncthreads();

    const unsigned* gl = (const unsigned*)gl4;   // cell view (half2 bits)
    const __half2*  gb = g16 + b * GSTRIDE;

    const int base = b * NPTS + blk * 4096;
    const float4 xv4 = ((const float4*)(x + base))[tid];
    float outre[4], outim[4];

#pragma unroll
    for (int q = 0; q < 4; ++q) {
        float xv = (q == 0) ? xv4.x : (q == 1) ? xv4.y : (q == 2) ? xv4.z : xv4.w;
        float fl   = xv * 8192.0f;                 // exact (2^13 scale)
        float cf   = ceilf(fl);
        int   c    = (int)cf;
        float frac = cf - fl;                      // [0,1)
        int   wr0  = (c + 12284) & (NGRID - 1);    // (c-4+n/2) mod n

        // LDS taps 0..3 (adjacent dwords; merges into 2x ds_read2_b32)
        unsigned c0 = gl[wr0 + 0];
        unsigned c1 = gl[wr0 + 1];
        unsigned c2 = gl[wr0 + 2];
        unsigned c3 = gl[wr0 + 3];
        // global taps 4..7 (L1-resident slab)
        float2 g4 = __half22float2(gb[wr0 + 4]);
        float2 g5 = __half22float2(gb[wr0 + 5]);
        float2 g6 = __half22float2(gb[wr0 + 6]);
        float2 g7 = __half22float2(gb[wr0 + 7]);

        float re = 0.0f, im = 0.0f;
#define NFFT_TAP(L, GX, GY) do {                                    \
            float u_    = (float)(4 - (L)) - frac;                  \
            float arg2_ = fmaf(-u_, u_, 16.0f);                     \
            float r_    = rsqrtf(arg2_);                            \
            float z_    = arg2_ * r_ * 4.71238898038468986f;        \
            float w_    = __expf(z_) * r_;                          \
            w_ = (arg2_ > 0.0f) ? w_ : 0.0f;                        \
            re = fmaf(w_, (GX), re);                                \
            im = fmaf(w_, (GY), im);                                \
        } while (0)
        {
            float2 t0 = h2f(c0); NFFT_TAP(0, t0.x, t0.y);
            float2 t1 = h2f(c1); NFFT_TAP(1, t1.x, t1.y);
            float2 t2 = h2f(c2); NFFT_TAP(2, t2.x, t2.y);
            float2 t3 = h2f(c3); NFFT_TAP(3, t3.x, t3.y);
            NFFT_TAP(4, g4.x, g4.y);
            NFFT_TAP(5, g5.x, g5.y);
            NFFT_TAP(6, g6.x, g6.y);
            NFFT_TAP(7, g7.x, g7.y);
        }
#undef NFFT_TAP
        outre[q] = re * OSCALE;
        outim[q] = im * OSCALE;
    }

    if (cplx) {
        float2* o = ((float2*)out) + base + tid * 4;
        o[0] = make_float2(outre[0], outim[0]);
        o[1] = make_float2(outre[1], outim[1]);
        o[2] = make_float2(outre[2], outim[2]);
        o[3] = make_float2(outre[3], outim[3]);
    } else {
        ((float4*)(out + base))[tid] =
            make_float4(outre[0], outre[1], outre[2], outre[3]);
    }
}

// ---------------------------------------------------------------------------
// Fallback: fully fused single kernel (proven R4/R7) if d_ws too small.
// ---------------------------------------------------------------------------
__global__ __launch_bounds__(1024) void nfft_fused_kernel(
    const float* __restrict__ x, const float* __restrict__ fr,
    const float* __restrict__ fi, float* __restrict__ out, int cplx)
{
    __shared__ float2 buf[NGRID];
    const int b   = blockIdx.x >> 5;
    const int blk = blockIdx.x & 31;
    const int tid = threadIdx.x;

    for (int j = tid; j < NGRID; j += 1024) {
        float2 v = make_float2(0.0f, 0.0f);
        if (j >= 2048 && j < 6144) {
            int fidx = j - 2048;
            float inv = deconv_signed(fidx);
            v.x = fr[b * NMODES + fidx] * inv;
            v.y = fi[b * NMODES + fidx] * inv;
        }
        buf[j] = v;
    }
    __syncthreads();

    for (int s = 12; s >= 0; --s) {
        const int   half = 1 << s;
        const float tscl = -0.5f / (float)half;
#pragma unroll
        for (int ii = 0; ii < 4; ++ii) {
            int i = tid + ii * 1024;
            int pos = i & (half - 1);
            int idx = ((i ^ pos) << 1) | pos;
            float sn = __builtin_amdgcn_sinf(tscl * (float)pos);
            float cs = __builtin_amdgcn_cosf(tscl * (float)pos);
            float2 a = buf[idx];
            float2 c = buf[idx + half];
            buf[idx] = make_float2(a.x + c.x, a.y + c.y);
            float2 d = make_float2(a.x - c.x, a.y - c.y);
            buf[idx + half] = make_float2(d.x * cs - d.y * sn,
                                          d.x * sn + d.y * cs);
        }
        __syncthreads();
    }

    const int base = b * NPTS + blk * 4096;
    for (int p = tid; p < 4096; p += 1024) {
        float xv   = x[base + p];
        float fl   = xv * 8192.0f;
        int   c    = (int)ceilf(fl);
        float frac = (float)c - fl;
        float re = 0.0f, im = 0.0f;
#pragma unroll
        for (int l = 0; l < 8; ++l) {
            int   ind  = c - 4 + l;
            float u    = (float)(4 - l) - frac;
            float arg2 = 16.0f - u * u;
            float w    = 0.0f;
            if (arg2 > 0.0f) {
                float r   = rsqrtf(arg2);
                float arg = arg2 * r;
                float z   = 4.71238898038468986f * arg;
                w = (__expf(z) - __expf(-z)) * 0.15915494309189533577f * r;
            }
            if (ind & 1) w = -w;
            int wr = (ind + 4096) & (NGRID - 1);
            int rb = (int)(__brev((unsigned)wr) >> 19);
            float2 gv = buf[rb];
            re = fmaf(w, gv.x, re);
            im = fmaf(w, gv.y, im);
        }
        if (cplx) ((float2*)out)[base + p] = make_float2(re, im);
        else      out[base + p] = re;
    }
}

extern "C" void kernel_launch(void* const* d_in, const int* in_sizes, int n_in,
                              void* d_out, int out_size, void* d_ws, size_t ws_size,
                              hipStream_t stream) {
    (void)in_sizes; (void)n_in;
    const float* x  = (const float*)d_in[0];
    const float* fr = (const float*)d_in[1];
    const float* fi = (const float*)d_in[2];

    const int cplx = (out_size >= BATCH * NPTS * 2) ? 1 : 0;
    const size_t g_bytes = (size_t)BATCH * GSTRIDE * sizeof(__half2);  // 525 KB

    if (ws_size >= g_bytes) {
        __half2* g16 = (__half2*)d_ws;
        nfft_fft_kernel<<<BATCH * 16, 256, 0, stream>>>(fr, fi, g16);
        nfft_interp_kernel<<<BATCH * 32, 1024, 0, stream>>>(
            x, g16, (float*)d_out, cplx);
    } else {
        nfft_fused_kernel<<<BATCH * 32, 1024, 0, stream>>>(
            x, fr, fi, (float*)d_out, cplx);
    }
}

// Round 17
// 19.264 us; speedup vs baseline: 1.1691x; 1.1691x over previous
//
#include <hip/hip_runtime.h>
#include <hip/hip_fp16.h>
#include <math.h>

#define NMODES 4096
#define NGRID  8192
#define BATCH  16
#define NPTS   131072
#define GSTRIDE 8200                    // 8192 + 8 wrap cells (u32 each); %4==0
#define GSCALE 1048576.0f               // 2^20 (exact)
#define OSCALE 1.5178830414797062e-07f  // 1/(2*pi*2^20)

__device__ __forceinline__ float2 cmul(float2 a, float2 b) {
    return make_float2(a.x * b.x - a.y * b.y, a.x * b.y + a.y * b.x);
}

// ---------------------------------------------------------------------------
// Deconvolution factor: (-1)^fidx / phi_hat(fidx), I0 asymptotic (z~18).
// ---------------------------------------------------------------------------
__device__ __forceinline__ float deconv_signed(int fidx) {
    float k = (float)(fidx - 2048);
    float t = k * 7.66990393942820614e-4f;                 // 2*pi*k/n
    float z = 4.0f * sqrtf(22.2066099024510563f - t * t);  // m*sqrt(b^2-t^2)
    float iz = 1.0f / z;
    float p  = 1.0f + iz * (0.125f + iz * (0.0703125f +
               iz * (0.0732421875f + iz * 0.112152099609375f)));
    float phi = __expf(z) * p * rsqrtf(6.28318530717958648f * z);
    float s = (fidx & 1) ? -1.0f : 1.0f;
    return s / phi;
}

// ---------------------------------------------------------------------------
// Merged four-step FFT (byte-identical to green R12/R15). One block per
// (batch, k1); writes packed scaled fp16 cells + 8 wrap cells.
// ---------------------------------------------------------------------------
__global__ __launch_bounds__(256) void nfft_fft_kernel(
    const float* __restrict__ fr, const float* __restrict__ fi,
    __half2* __restrict__ g16)
{
    __shared__ float2 hbuf[NMODES];  // 32 KB
    __shared__ float2 fbuf[512];     // 4 KB
    __shared__ float2 w16[16];

    const int b   = blockIdx.x >> 4;
    const int k1  = blockIdx.x & 15;
    const int tid = threadIdx.x;

    if (tid < 16) {
        float tn = -(float)tid * 0.0625f;   // -t/16 turns
        w16[tid] = make_float2(__builtin_amdgcn_cosf(tn),
                               __builtin_amdgcn_sinf(tn));
    }
#pragma unroll
    for (int i = 0; i < 16; ++i) {          // coalesced: lanes consecutive
        int fidx = tid + i * 256;
        float inv = deconv_signed(fidx);    // includes (-1)^j sign
        hbuf[fidx] = make_float2(fr[b * NMODES + fidx] * inv,
                                 fi[b * NMODES + fidx] * inv);
    }
    __syncthreads();

#pragma unroll
    for (int hi = 0; hi < 2; ++hi) {
        int n2 = tid + hi * 256;
        float2 acc = make_float2(0.0f, 0.0f);
#pragma unroll
        for (int r = 0; r < 8; ++r) {
            float2 w = w16[((r + 4) * k1) & 15];
            float2 h = hbuf[n2 + 512 * r];
            acc.x = fmaf(h.x, w.x, fmaf(-h.y, w.y, acc.x));
            acc.y = fmaf(h.x, w.y, fmaf( h.y, w.x, acc.y));
        }
        float tn = -(float)(n2 * k1) * 1.220703125e-4f;  // -(n2*k1)/8192 turns
        float2 tw = make_float2(__builtin_amdgcn_cosf(tn),
                                __builtin_amdgcn_sinf(tn));
        int rb = (int)(__brev((unsigned)n2) >> 23);      // 9-bit reversal
        fbuf[rb] = cmul(acc, tw);
    }
    __syncthreads();

    for (int s = 0; s <= 8; ++s) {
        const int   half = 1 << s;
        const float tscl = -0.5f / (float)half;          // turns per pos
        int pos = tid & (half - 1);
        int idx = ((tid ^ pos) << 1) | pos;
        float sn = __builtin_amdgcn_sinf(tscl * (float)pos);
        float cs = __builtin_amdgcn_cosf(tscl * (float)pos);
        float2 a = fbuf[idx];
        float2 t = fbuf[idx + half];
        float2 bt = make_float2(t.x * cs - t.y * sn,
                                t.x * sn + t.y * cs);
        fbuf[idx]        = make_float2(a.x + bt.x, a.y + bt.y);
        fbuf[idx + half] = make_float2(a.x - bt.x, a.y - bt.y);
        __syncthreads();
    }

    const float s2 = ((k1 & 1) ? -1.0f : 1.0f) * GSCALE;  // sign * 2^20
    __half2* base = g16 + b * GSTRIDE + k1;
#pragma unroll
    for (int ii = 0; ii < 2; ++ii) {
        int j = tid + ii * 256;
        float2 v = fbuf[j];
        base[16 * j] = __floats2half2_rn(v.x * s2, v.y * s2);
    }
    if (tid == 0 && k1 < 8) {   // wrap cell: cell k1 duplicated at 8192+k1
        float2 v = fbuf[0];
        g16[b * GSTRIDE + NGRID + k1] = __floats2half2_rn(v.x * s2, v.y * s2);
    }
}

// ---------------------------------------------------------------------------
// Interp (R15 structure, proven 21.7us) with 6 taps instead of 8:
// edge taps l=0,7 have |u| in (3,4] -> w <= 1.6e4 vs center 7.6e6; their
// output contribution (<~0.5 worst case) is far inside the 6.0 budget.
// Bonus: for l in [1,6], arg2 = 16-u^2 >= 7 > 0 always -> no NaN select.
// ---------------------------------------------------------------------------
__global__ __launch_bounds__(1024) void nfft_interp_kernel(
    const float* __restrict__ x, const __half2* __restrict__ g16,
    float* __restrict__ out, int cplx)
{
    const int b   = blockIdx.x & 15;    // co-resident blocks share a batch
    const int blk = blockIdx.x >> 4;
    const int tid = threadIdx.x;

    const __half2* gb = g16 + b * GSTRIDE;
    const int base = b * NPTS + blk * 4096;
    const float4 xv4 = ((const float4*)(x + base))[tid];
    float outre[4], outim[4];

#pragma unroll
    for (int q = 0; q < 4; ++q) {
        float xv = (q == 0) ? xv4.x : (q == 1) ? xv4.y : (q == 2) ? xv4.z : xv4.w;
        float fl   = xv * 8192.0f;                 // exact (2^13 scale)
        float cf   = ceilf(fl);
        int   c    = (int)cf;
        float frac = cf - fl;                      // [0,1)
        int   wr0  = (c + 12284) & (NGRID - 1);    // (c-4+n/2) mod n
        const __half2* gp = gb + wr0;              // taps: gp[1..6]
        float re = 0.0f, im = 0.0f;
#pragma unroll
        for (int l = 1; l < 7; ++l) {
            float u    = (float)(4 - l) - frac;    // n*x - ind, |u| <= 3
            float arg2 = fmaf(-u, u, 16.0f);       // m^2 - u^2 >= 7 > 0
            float r    = rsqrtf(arg2);             // 1/arg
            float z    = arg2 * r * 4.71238898038468986f;  // b*arg
            float w    = __expf(z) * r;            // ~2*sinh(z)/arg (scaled later)
            float2 gv = __half22float2(gp[l]);
            re = fmaf(w, gv.x, re);
            im = fmaf(w, gv.y, im);
        }
        outre[q] = re * OSCALE;
        outim[q] = im * OSCALE;
    }

    if (cplx) {
        float2* o = ((float2*)out) + base + tid * 4;
        o[0] = make_float2(outre[0], outim[0]);
        o[1] = make_float2(outre[1], outim[1]);
        o[2] = make_float2(outre[2], outim[2]);
        o[3] = make_float2(outre[3], outim[3]);
    } else {
        ((float4*)(out + base))[tid] =
            make_float4(outre[0], outre[1], outre[2], outre[3]);
    }
}

// ---------------------------------------------------------------------------
// Fallback: fully fused single kernel (proven R4/R7) if d_ws too small.
// ---------------------------------------------------------------------------
__global__ __launch_bounds__(1024) void nfft_fused_kernel(
    const float* __restrict__ x, const float* __restrict__ fr,
    const float* __restrict__ fi, float* __restrict__ out, int cplx)
{
    __shared__ float2 buf[NGRID];
    const int b   = blockIdx.x >> 5;
    const int blk = blockIdx.x & 31;
    const int tid = threadIdx.x;

    for (int j = tid; j < NGRID; j += 1024) {
        float2 v = make_float2(0.0f, 0.0f);
        if (j >= 2048 && j < 6144) {
            int fidx = j - 2048;
            float inv = deconv_signed(fidx);
            v.x = fr[b * NMODES + fidx] * inv;
            v.y = fi[b * NMODES + fidx] * inv;
        }
        buf[j] = v;
    }
    __syncthreads();

    for (int s = 12; s >= 0; --s) {
        const int   half = 1 << s;
        const float tscl = -0.5f / (float)half;
#pragma unroll
        for (int ii = 0; ii < 4; ++ii) {
            int i = tid + ii * 1024;
            int pos = i & (half - 1);
            int idx = ((i ^ pos) << 1) | pos;
            float sn = __builtin_amdgcn_sinf(tscl * (float)pos);
            float cs = __builtin_amdgcn_cosf(tscl * (float)pos);
            float2 a = buf[idx];
            float2 c = buf[idx + half];
            buf[idx] = make_float2(a.x + c.x, a.y + c.y);
            float2 d = make_float2(a.x - c.x, a.y - c.y);
            buf[idx + half] = make_float2(d.x * cs - d.y * sn,
                                          d.x * sn + d.y * cs);
        }
        __syncthreads();
    }

    const int base = b * NPTS + blk * 4096;
    for (int p = tid; p < 4096; p += 1024) {
        float xv   = x[base + p];
        float fl   = xv * 8192.0f;
        int   c    = (int)ceilf(fl);
        float frac = (float)c - fl;
        float re = 0.0f, im = 0.0f;
#pragma unroll
        for (int l = 0; l < 8; ++l) {
            int   ind  = c - 4 + l;
            float u    = (float)(4 - l) - frac;
            float arg2 = 16.0f - u * u;
            float w    = 0.0f;
            if (arg2 > 0.0f) {
                float r   = rsqrtf(arg2);
                float arg = arg2 * r;
                float z   = 4.71238898038468986f * arg;
                w = (__expf(z) - __expf(-z)) * 0.15915494309189533577f * r;
            }
            if (ind & 1) w = -w;
            int wr = (ind + 4096) & (NGRID - 1);
            int rb = (int)(__brev((unsigned)wr) >> 19);
            float2 gv = buf[rb];
            re = fmaf(w, gv.x, re);
            im = fmaf(w, gv.y, im);
        }
        if (cplx) ((float2*)out)[base + p] = make_float2(re, im);
        else      out[base + p] = re;
    }
}

extern "C" void kernel_launch(void* const* d_in, const int* in_sizes, int n_in,
                              void* d_out, int out_size, void* d_ws, size_t ws_size,
                              hipStream_t stream) {
    (void)in_sizes; (void)n_in;
    const float* x  = (const float*)d_in[0];
    const float* fr = (const float*)d_in[1];
    const float* fi = (const float*)d_in[2];

    const int cplx = (out_size >= BATCH * NPTS * 2) ? 1 : 0;
    const size_t g_bytes = (size_t)BATCH * GSTRIDE * sizeof(__half2);  // 525 KB

    if (ws_size >= g_bytes) {
        __half2* g16 = (__half2*)d_ws;
        nfft_fft_kernel<<<BATCH * 16, 256, 0, stream>>>(fr, fi, g16);
        nfft_interp_kernel<<<BATCH * 32, 1024, 0, stream>>>(
            x, g16, (float*)d_out, cplx);
    } else {
        nfft_fused_kernel<<<BATCH * 32, 1024, 0, stream>>>(
            x, fr, fi, (float*)d_out, cplx);
    }
}

// Round 18
// 19.239 us; speedup vs baseline: 1.1706x; 1.0013x over previous
//
#include <hip/hip_runtime.h>
#include <hip/hip_fp16.h>
#include <math.h>

#define NMODES 4096
#define NGRID  8192
#define BATCH  16
#define NPTS   131072
#define GSTRIDE 8200                    // 8192 + 8 wrap cells (u32 each); %4==0
#define GSCALE 1048576.0f               // 2^20 (exact)
#define OSCALE 1.5178830414797062e-07f  // 1/(2*pi*2^20)

__device__ __forceinline__ float2 cmul(float2 a, float2 b) {
    return make_float2(a.x * b.x - a.y * b.y, a.x * b.y + a.y * b.x);
}

__device__ __forceinline__ float2 h2f(unsigned v) {
    __half2 h = *reinterpret_cast<__half2*>(&v);
    return __half22float2(h);
}

// 4B-aligned wide-load carriers: gfx950 handles unaligned global dwordx4/x2
// in hardware, so these emit single wide loads (worst case: split to dwords
// = exactly the R17 behavior).
struct __align__(4) UA4 { unsigned v0, v1, v2, v3; };
struct __align__(4) UA2 { unsigned v0, v1; };

// ---------------------------------------------------------------------------
// Deconvolution factor: (-1)^fidx / phi_hat(fidx), I0 asymptotic (z~18).
// ---------------------------------------------------------------------------
__device__ __forceinline__ float deconv_signed(int fidx) {
    float k = (float)(fidx - 2048);
    float t = k * 7.66990393942820614e-4f;                 // 2*pi*k/n
    float z = 4.0f * sqrtf(22.2066099024510563f - t * t);  // m*sqrt(b^2-t^2)
    float iz = 1.0f / z;
    float p  = 1.0f + iz * (0.125f + iz * (0.0703125f +
               iz * (0.0732421875f + iz * 0.112152099609375f)));
    float phi = __expf(z) * p * rsqrtf(6.28318530717958648f * z);
    float s = (fidx & 1) ? -1.0f : 1.0f;
    return s / phi;
}

// ---------------------------------------------------------------------------
// Merged four-step FFT (byte-identical to green R12/R15/R17). One block per
// (batch, k1); writes packed scaled fp16 cells + 8 wrap cells.
// ---------------------------------------------------------------------------
__global__ __launch_bounds__(256) void nfft_fft_kernel(
    const float* __restrict__ fr, const float* __restrict__ fi,
    __half2* __restrict__ g16)
{
    __shared__ float2 hbuf[NMODES];  // 32 KB
    __shared__ float2 fbuf[512];     // 4 KB
    __shared__ float2 w16[16];

    const int b   = blockIdx.x >> 4;
    const int k1  = blockIdx.x & 15;
    const int tid = threadIdx.x;

    if (tid < 16) {
        float tn = -(float)tid * 0.0625f;   // -t/16 turns
        w16[tid] = make_float2(__builtin_amdgcn_cosf(tn),
                               __builtin_amdgcn_sinf(tn));
    }
#pragma unroll
    for (int i = 0; i < 16; ++i) {          // coalesced: lanes consecutive
        int fidx = tid + i * 256;
        float inv = deconv_signed(fidx);    // includes (-1)^j sign
        hbuf[fidx] = make_float2(fr[b * NMODES + fidx] * inv,
                                 fi[b * NMODES + fidx] * inv);
    }
    __syncthreads();

#pragma unroll
    for (int hi = 0; hi < 2; ++hi) {
        int n2 = tid + hi * 256;
        float2 acc = make_float2(0.0f, 0.0f);
#pragma unroll
        for (int r = 0; r < 8; ++r) {
            float2 w = w16[((r + 4) * k1) & 15];
            float2 h = hbuf[n2 + 512 * r];
            acc.x = fmaf(h.x, w.x, fmaf(-h.y, w.y, acc.x));
            acc.y = fmaf(h.x, w.y, fmaf( h.y, w.x, acc.y));
        }
        float tn = -(float)(n2 * k1) * 1.220703125e-4f;  // -(n2*k1)/8192 turns
        float2 tw = make_float2(__builtin_amdgcn_cosf(tn),
                                __builtin_amdgcn_sinf(tn));
        int rb = (int)(__brev((unsigned)n2) >> 23);      // 9-bit reversal
        fbuf[rb] = cmul(acc, tw);
    }
    __syncthreads();

    for (int s = 0; s <= 8; ++s) {
        const int   half = 1 << s;
        const float tscl = -0.5f / (float)half;          // turns per pos
        int pos = tid & (half - 1);
        int idx = ((tid ^ pos) << 1) | pos;
        float sn = __builtin_amdgcn_sinf(tscl * (float)pos);
        float cs = __builtin_amdgcn_cosf(tscl * (float)pos);
        float2 a = fbuf[idx];
        float2 t = fbuf[idx + half];
        float2 bt = make_float2(t.x * cs - t.y * sn,
                                t.x * sn + t.y * cs);
        fbuf[idx]        = make_float2(a.x + bt.x, a.y + bt.y);
        fbuf[idx + half] = make_float2(a.x - bt.x, a.y - bt.y);
        __syncthreads();
    }

    const float s2 = ((k1 & 1) ? -1.0f : 1.0f) * GSCALE;  // sign * 2^20
    __half2* base = g16 + b * GSTRIDE + k1;
#pragma unroll
    for (int ii = 0; ii < 2; ++ii) {
        int j = tid + ii * 256;
        float2 v = fbuf[j];
        base[16 * j] = __floats2half2_rn(v.x * s2, v.y * s2);
    }
    if (tid == 0 && k1 < 8) {   // wrap cell: cell k1 duplicated at 8192+k1
        float2 v = fbuf[0];
        g16[b * GSTRIDE + NGRID + k1] = __floats2half2_rn(v.x * s2, v.y * s2);
    }
}

// ---------------------------------------------------------------------------
// Interp (R17's 6-tap window math, proven 19.26us) with the 6 scattered
// dword taps replaced by ONE unaligned dwordx4 + ONE unaligned dwordx2
// (exact 24 bytes, no selects): 2 scatter requests per point instead of 6.
// ---------------------------------------------------------------------------
__global__ __launch_bounds__(1024) void nfft_interp_kernel(
    const float* __restrict__ x, const __half2* __restrict__ g16,
    float* __restrict__ out, int cplx)
{
    const int b   = blockIdx.x & 15;    // co-resident blocks share a batch
    const int blk = blockIdx.x >> 4;
    const int tid = threadIdx.x;

    const unsigned* gu = (const unsigned*)(g16 + b * GSTRIDE);
    const int base = b * NPTS + blk * 4096;
    const float4 xv4 = ((const float4*)(x + base))[tid];
    float outre[4], outim[4];

#pragma unroll
    for (int q = 0; q < 4; ++q) {
        float xv = (q == 0) ? xv4.x : (q == 1) ? xv4.y : (q == 2) ? xv4.z : xv4.w;
        float fl   = xv * 8192.0f;                 // exact (2^13 scale)
        float cf   = ceilf(fl);
        int   c    = (int)cf;
        float frac = cf - fl;                      // [0,1)
        int   wr0  = (c + 12284) & (NGRID - 1);    // (c-4+n/2) mod n

        // taps 1..6 = cells wr0+1 .. wr0+6 (max 8197 < 8200 incl. wrap pad)
        UA4 A = *reinterpret_cast<const UA4*>(gu + wr0 + 1);
        UA2 B = *reinterpret_cast<const UA2*>(gu + wr0 + 5);

        float re = 0.0f, im = 0.0f;
#define NFFT_TAP(L, TV) do {                                        \
            float u_    = (float)(4 - (L)) - frac;                  \
            float arg2_ = fmaf(-u_, u_, 16.0f);  /* >= 7 > 0 */     \
            float r_    = rsqrtf(arg2_);                            \
            float z_    = arg2_ * r_ * 4.71238898038468986f;        \
            float w_    = __expf(z_) * r_;                          \
            float2 gv_  = h2f(TV);                                  \
            re = fmaf(w_, gv_.x, re);                               \
            im = fmaf(w_, gv_.y, im);                               \
        } while (0)
        NFFT_TAP(1, A.v0); NFFT_TAP(2, A.v1); NFFT_TAP(3, A.v2);
        NFFT_TAP(4, A.v3); NFFT_TAP(5, B.v0); NFFT_TAP(6, B.v1);
#undef NFFT_TAP
        outre[q] = re * OSCALE;
        outim[q] = im * OSCALE;
    }

    if (cplx) {
        float2* o = ((float2*)out) + base + tid * 4;
        o[0] = make_float2(outre[0], outim[0]);
        o[1] = make_float2(outre[1], outim[1]);
        o[2] = make_float2(outre[2], outim[2]);
        o[3] = make_float2(outre[3], outim[3]);
    } else {
        ((float4*)(out + base))[tid] =
            make_float4(outre[0], outre[1], outre[2], outre[3]);
    }
}

// ---------------------------------------------------------------------------
// Fallback: fully fused single kernel (proven R4/R7) if d_ws too small.
// ---------------------------------------------------------------------------
__global__ __launch_bounds__(1024) void nfft_fused_kernel(
    const float* __restrict__ x, const float* __restrict__ fr,
    const float* __restrict__ fi, float* __restrict__ out, int cplx)
{
    __shared__ float2 buf[NGRID];
    const int b   = blockIdx.x >> 5;
    const int blk = blockIdx.x & 31;
    const int tid = threadIdx.x;

    for (int j = tid; j < NGRID; j += 1024) {
        float2 v = make_float2(0.0f, 0.0f);
        if (j >= 2048 && j < 6144) {
            int fidx = j - 2048;
            float inv = deconv_signed(fidx);
            v.x = fr[b * NMODES + fidx] * inv;
            v.y = fi[b * NMODES + fidx] * inv;
        }
        buf[j] = v;
    }
    __syncthreads();

    for (int s = 12; s >= 0; --s) {
        const int   half = 1 << s;
        const float tscl = -0.5f / (float)half;
#pragma unroll
        for (int ii = 0; ii < 4; ++ii) {
            int i = tid + ii * 1024;
            int pos = i & (half - 1);
            int idx = ((i ^ pos) << 1) | pos;
            float sn = __builtin_amdgcn_sinf(tscl * (float)pos);
            float cs = __builtin_amdgcn_cosf(tscl * (float)pos);
            float2 a = buf[idx];
            float2 c = buf[idx + half];
            buf[idx] = make_float2(a.x + c.x, a.y + c.y);
            float2 d = make_float2(a.x - c.x, a.y - c.y);
            buf[idx + half] = make_float2(d.x * cs - d.y * sn,
                                          d.x * sn + d.y * cs);
        }
        __syncthreads();
    }

    const int base = b * NPTS + blk * 4096;
    for (int p = tid; p < 4096; p += 1024) {
        float xv   = x[base + p];
        float fl   = xv * 8192.0f;
        int   c    = (int)ceilf(fl);
        float frac = (float)c - fl;
        float re = 0.0f, im = 0.0f;
#pragma unroll
        for (int l = 0; l < 8; ++l) {
            int   ind  = c - 4 + l;
            float u    = (float)(4 - l) - frac;
            float arg2 = 16.0f - u * u;
            float w    = 0.0f;
            if (arg2 > 0.0f) {
                float r   = rsqrtf(arg2);
                float arg = arg2 * r;
                float z   = 4.71238898038468986f * arg;
                w = (__expf(z) - __expf(-z)) * 0.15915494309189533577f * r;
            }
            if (ind & 1) w = -w;
            int wr = (ind + 4096) & (NGRID - 1);
            int rb = (int)(__brev((unsigned)wr) >> 19);
            float2 gv = buf[rb];
            re = fmaf(w, gv.x, re);
            im = fmaf(w, gv.y, im);
        }
        if (cplx) ((float2*)out)[base + p] = make_float2(re, im);
        else      out[base + p] = re;
    }
}

extern "C" void kernel_launch(void* const* d_in, const int* in_sizes, int n_in,
                              void* d_out, int out_size, void* d_ws, size_t ws_size,
                              hipStream_t stream) {
    (void)in_sizes; (void)n_in;
    const float* x  = (const float*)d_in[0];
    const float* fr = (const float*)d_in[1];
    const float* fi = (const float*)d_in[2];

    const int cplx = (out_size >= BATCH * NPTS * 2) ? 1 : 0;
    const size_t g_bytes = (size_t)BATCH * GSTRIDE * sizeof(__half2);  // 525 KB

    if (ws_size >= g_bytes) {
        __half2* g16 = (__half2*)d_ws;
        nfft_fft_kernel<<<BATCH * 16, 256, 0, stream>>>(fr, fi, g16);
        nfft_interp_kernel<<<BATCH * 32, 1024, 0, stream>>>(
            x, g16, (float*)d_out, cplx);
    } else {
        nfft_fused_kernel<<<BATCH * 32, 1024, 0, stream>>>(
            x, fr, fi, (float*)d_out, cplx);
    }
}